// Round 1
// baseline (487.973 us; speedup 1.0000x reference)
//
#include <hip/hip_runtime.h>
#include <hip/hip_bf16.h>
#include <cstdint>

// ---------------------------------------------------------------------------
// TransBlock: pre-LN transformer encoder block, bf16 MFMA compute, fp32 I/O.
// B=4 S=2048 E=1024 H=16 Dh=64 Dff=4096.  M = B*S = 8192 rows.
// ---------------------------------------------------------------------------

typedef __attribute__((ext_vector_type(8))) short bf16x8;   // 4 VGPRs, MFMA A/B frag
typedef __attribute__((ext_vector_type(4))) float f32x4;    // MFMA C/D frag

#define LDSAS __attribute__((address_space(3)))
#define GLBAS __attribute__((address_space(1)))

#define CQK 0.18033688011112044f   // (1/8) * log2(e), folded into Q at QKV epilogue

__device__ __forceinline__ unsigned short f2bf(float f) {
  union { float f; unsigned u; } c; c.f = f;
  unsigned u = c.u + 0x7fffu + ((c.u >> 16) & 1u);   // RNE
  return (unsigned short)(u >> 16);
}

__device__ __forceinline__ unsigned pk2(float a, float b) {  // v_cvt_pk path
  __hip_bfloat162 h = __float22bfloat162_rn(make_float2(a, b));
  union { __hip_bfloat162 h; unsigned u; } c; c.h = h; return c.u;
}

// async global->LDS, 16B/lane, dest = wave-uniform base + lane*16
__device__ __forceinline__ void async16(const unsigned short* g, unsigned short* l) {
  __builtin_amdgcn_global_load_lds((const GLBAS unsigned int*)g,
                                   (LDSAS unsigned int*)l, 16, 0, 0);
}

// ---------------------------------------------------------------------------
// cvt_all: all six fp32 weight arrays -> bf16 workspace in ONE launch.
// ---------------------------------------------------------------------------
__global__ void cvt_all(const float* __restrict__ q, const float* __restrict__ k,
                        const float* __restrict__ v, const float* __restrict__ o,
                        const float* __restrict__ w1, const float* __restrict__ w2,
                        unsigned short* __restrict__ wsb) {
  const long i = (long)blockIdx.x * 256 + threadIdx.x;   // float4 index
  const float* src; unsigned short* dst; long off;
  if (i < 1048576) {
    const long seg = i >> 18, o4 = i & 262143;
    src = (seg == 0) ? q : (seg == 1) ? k : (seg == 2) ? v : o;
    dst = wsb + ((seg == 3) ? 3145728L : seg * 1048576L);
    off = o4;
  } else if (i < 2097152) {
    src = w1; dst = wsb + 4194304; off = i - 1048576;
  } else {
    src = w2; dst = wsb + 8388608; off = i - 2097152;
  }
  const float4 vv = ((const float4*)src)[off];
  ushort4 r;
  r.x = f2bf(vv.x); r.y = f2bf(vv.y); r.z = f2bf(vv.z); r.w = f2bf(vv.w);
  ((ushort4*)dst)[off] = r;
}

// ---------------------------------------------------------------------------
// LayerNorm: one block per row of 1024, fp32 in -> bf16 out
// ---------------------------------------------------------------------------
__global__ void ln_fwd(const float* __restrict__ x, const float* __restrict__ g,
                       const float* __restrict__ bb, unsigned short* __restrict__ outp) {
  const int row = blockIdx.x, tid = threadIdx.x;
  const float4 v = ((const float4*)(x + (long)row * 1024))[tid];
  float s  = v.x + v.y + v.z + v.w;
  float sq = v.x * v.x + v.y * v.y + v.z * v.z + v.w * v.w;
#pragma unroll
  for (int off = 1; off < 64; off <<= 1) {
    s  += __shfl_xor(s, off);
    sq += __shfl_xor(sq, off);
  }
  __shared__ float red[8];
  const int wv = tid >> 6, lane = tid & 63;
  if (lane == 0) { red[wv] = s; red[4 + wv] = sq; }
  __syncthreads();
  s  = red[0] + red[1] + red[2] + red[3];
  sq = red[4] + red[5] + red[6] + red[7];
  const float mu  = s * (1.f / 1024.f);
  const float var = sq * (1.f / 1024.f) - mu * mu;
  const float rstd = rsqrtf(var + 1e-5f);
  const float4 gv = ((const float4*)g)[tid];
  const float4 bv = ((const float4*)bb)[tid];
  ushort4 o;
  o.x = f2bf((v.x - mu) * rstd * gv.x + bv.x);
  o.y = f2bf((v.y - mu) * rstd * gv.y + bv.y);
  o.z = f2bf((v.z - mu) * rstd * gv.z + bv.z);
  o.w = f2bf((v.w - mu) * rstd * gv.w + bv.w);
  ((ushort4*)(outp + (long)row * 1024))[tid] = o;
}

// ---------------------------------------------------------------------------
// B^T GEMM (128x128 tile, 2-barrier structure) kept for N=1024 GEMMs where a
// 256^2 grid would only fill half the CUs (Wo, W2).
// EPI: 1 = +bias +fp32 residual -> fp32
// ---------------------------------------------------------------------------
template <int EPI>
__launch_bounds__(256, 3)
__global__ void gemm_bt(const unsigned short* __restrict__ A,
                        const unsigned short* __restrict__ B,
                        void* __restrict__ Cout,
                        const float* __restrict__ bias,
                        const float* __restrict__ res,
                        int M, int N, int K) {
  __shared__ __align__(16) unsigned short As[128 * 64];   // 16 KB each
  __shared__ __align__(16) unsigned short Bs[128 * 64];
  const int tid  = threadIdx.x;
  const int lane = tid & 63;
  const int wvu  = __builtin_amdgcn_readfirstlane(tid >> 6);  // wave id, SGPR
  const int quad = lane >> 4, l16 = lane & 15;
  const int wm = wvu >> 1, wn = wvu & 1;

  const int gx = gridDim.x;
  const int id = blockIdx.y * gx + blockIdx.x;
  const int xcd = id & 7, slot = id >> 3;
  const int by = xcd * 8 + (slot & 7);
  const int bx = slot >> 3;
  const long m0 = (long)by * 128, n0 = (long)bx * 128;

  f32x4 acc[4][4];
#pragma unroll
  for (int i = 0; i < 4; i++)
#pragma unroll
    for (int j = 0; j < 4; j++) acc[i][j] = (f32x4){0.f, 0.f, 0.f, 0.f};

  const int rxA = l16 & 7;
  const int c0A = quad ^ rxA;              // kc=0 phys chunk for frag reads
  int srow[4], sgc[4];
#pragma unroll
  for (int j = 0; j < 4; ++j) {
    const int s = wvu * 256 + j * 64 + lane;
    srow[j] = s >> 3;
    sgc[j] = ((s & 7) ^ (srow[j] & 7)) * 8;
  }

  for (int k0 = 0; k0 < K; k0 += 64) {
    __syncthreads();
#pragma unroll
    for (int j = 0; j < 4; ++j) {
      const int db = (wvu * 256 + j * 64) * 8;   // wave-uniform LDS base (elems)
      async16(A + (m0 + srow[j]) * K + k0 + sgc[j], As + db);
      async16(B + (n0 + srow[j]) * K + k0 + sgc[j], Bs + db);
    }
    __syncthreads();

#pragma unroll
    for (int kc = 0; kc < 2; ++kc) {
      const int ch = (c0A ^ (kc * 4)) * 8;
      bf16x8 af[4], bfr[4];
#pragma unroll
      for (int t = 0; t < 4; ++t) {
        af[t]  = *(const bf16x8*)(As + (wm * 64 + t * 16 + l16) * 64 + ch);
        bfr[t] = *(const bf16x8*)(Bs + (wn * 64 + t * 16 + l16) * 64 + ch);
      }
#pragma unroll
      for (int mt = 0; mt < 4; ++mt)
#pragma unroll
        for (int nt = 0; nt < 4; ++nt)
          acc[mt][nt] = __builtin_amdgcn_mfma_f32_16x16x32_bf16(af[mt], bfr[nt],
                                                                acc[mt][nt], 0, 0, 0);
    }
  }

#pragma unroll
  for (int nt = 0; nt < 4; ++nt) {
    const long col = n0 + wn * 64 + nt * 16 + l16;
    float bv = 0.f;
    if (EPI == 1 || EPI == 2) bv = bias[col];
    const float scl = (EPI == 3 && col < 1024) ? CQK : 1.0f;
#pragma unroll
    for (int mt = 0; mt < 4; ++mt) {
#pragma unroll
      for (int r = 0; r < 4; ++r) {
        const long row = m0 + wm * 64 + mt * 16 + quad * 4 + r;
        const long idx = row * (long)N + col;
        float v = acc[mt][nt][r];
        if (EPI == 0) {
          ((unsigned short*)Cout)[idx] = f2bf(v);
        } else if (EPI == 1) {
          ((float*)Cout)[idx] = v + bv + res[idx];
        } else if (EPI == 2) {
          v += bv;
          ((unsigned short*)Cout)[idx] = f2bf(v > 0.f ? v : 0.f);
        } else {
          ((unsigned short*)Cout)[idx] = f2bf(v * scl);
        }
      }
    }
  }
}

// ---------------------------------------------------------------------------
// gemm256: 256x256 tile, BK=64, 8-phase counted-vmcnt schedule (T2+T3+T4+T5).
// 512 thr = 8 waves (2M x 4N); per-wave output 128x64 as 8 m-frags (rows
// mt*32+wm*16) x 4 n-frags (cols nt*64+wn*16).  LDS = 2 dbuf x 2 half x
// [128][64] for A and B = 128 KiB (dynamic).  XOR-chunk swizzle (proven
// 0-conflict in gemm_bt) on each [128][64] half.
//
// Schedule per iter (tiles t=2i -> buf0, u=2i+1 -> buf1), B-frags held in
// regs across phase pairs so LDS halves die a phase early:
//  p1 q0(t:A0,B0)  stage u.A1          p5 q0(u)  stage t2.A1
//  p2 q1(t:A1)     stage t2.B0         p6 q1(u)  stage t3.B0
//  p3 q2(t:A0,B1)                      p7 q2(u)
//  p4 q3(t:A1)     stage t2.A0,t2.B1   p8 q3(u)  stage t3.A0,t3.B1
//  p4/p8 end: s_waitcnt vmcnt(6)  (== next tile's 8 loads landed, 3
//  half-tiles = 6 loads still in flight).  Never vmcnt(0) in steady state.
// Requires grid = (M/256)*(N/256) with M=8192 (32 m-tiles).
// EPI: 2 = +bias, relu -> bf16 ; 3 = bf16, cols<1024 scaled by CQK
// ---------------------------------------------------------------------------
#define LDA4(AF, BUF, H)                                                        \
  do {                                                                          \
    const unsigned short* _p = As + ((BUF) * 2 + (H)) * 8192;                   \
    _Pragma("unroll") for (int _m = 0; _m < 4; ++_m) {                          \
      AF[_m][0] = *(const bf16x8*)(_p + (_m * 32 + rA) * 64 + chk0);            \
      AF[_m][1] = *(const bf16x8*)(_p + (_m * 32 + rA) * 64 + chk1);            \
    }                                                                           \
  } while (0)

#define LDB2(BF, BUF, H)                                                        \
  do {                                                                          \
    const unsigned short* _p = Bs + ((BUF) * 2 + (H)) * 8192;                   \
    _Pragma("unroll") for (int _n = 0; _n < 2; ++_n) {                          \
      BF[_n][0] = *(const bf16x8*)(_p + (_n * 64 + rB) * 64 + chk0);            \
      BF[_n][1] = *(const bf16x8*)(_p + (_n * 64 + rB) * 64 + chk1);            \
    }                                                                           \
  } while (0)

#define MFMA8(MB, NB, AF, BF)                                                   \
  do {                                                                          \
    _Pragma("unroll") for (int _m = 0; _m < 4; ++_m)                            \
    _Pragma("unroll") for (int _n = 0; _n < 2; ++_n) {                          \
      acc[(MB) + _m][(NB) + _n] = __builtin_amdgcn_mfma_f32_16x16x32_bf16(      \
          AF[_m][0], BF[_n][0], acc[(MB) + _m][(NB) + _n], 0, 0, 0);            \
      acc[(MB) + _m][(NB) + _n] = __builtin_amdgcn_mfma_f32_16x16x32_bf16(      \
          AF[_m][1], BF[_n][1], acc[(MB) + _m][(NB) + _n], 0, 0, 0);            \
    }                                                                           \
  } while (0)

#define PH_MID()                                                                \
  __builtin_amdgcn_s_barrier();                                                 \
  asm volatile("s_waitcnt lgkmcnt(0)" ::: "memory");                            \
  __builtin_amdgcn_sched_barrier(0);                                            \
  __builtin_amdgcn_s_setprio(1)

#define PH_END()                                                                \
  __builtin_amdgcn_s_setprio(0);                                                \
  __builtin_amdgcn_sched_barrier(0);                                            \
  __builtin_amdgcn_s_barrier();                                                 \
  __builtin_amdgcn_sched_barrier(0)

template <int EPI>
__launch_bounds__(512, 2)
__global__ void gemm256(const unsigned short* __restrict__ A,
                        const unsigned short* __restrict__ B,
                        void* __restrict__ Cout,
                        const float* __restrict__ bias,
                        int M, int N, int K) {
  extern __shared__ __align__(16) unsigned short lds[];
  unsigned short* As = lds;            // [2 buf][2 half][8192]  64 KB
  unsigned short* Bs = lds + 32768;    // [2 buf][2 half][8192]  64 KB

  const int tid  = threadIdx.x;
  const int lane = tid & 63;
  const int wv   = __builtin_amdgcn_readfirstlane(tid >> 6);  // 0..7
  const int quad = lane >> 4, l16 = lane & 15;
  const int wm = wv >> 2, wn = wv & 3;

  // XCD-aware remap: 32 m-tiles, each XCD owns a 4-tile m-band
  const int id = blockIdx.x;
  const int xcd = id & 7, slot = id >> 3;
  const int by = xcd * 4 + (slot & 3);
  const int bx = slot >> 2;
  const long m0 = (long)by * 256, n0 = (long)bx * 256;

  // staging constants: chunk s = j*512 + wv*64 + lane; row=s>>3, phys=s&7,
  // source logical chunk = phys ^ (row&7)
  const int s0 = wv * 64 + lane;
  const int r0 = s0 >> 3;
  const int c0 = (s0 ^ r0) & 7;
  const int s1 = 512 + s0;
  const int r1 = s1 >> 3;
  const int c1 = (s1 ^ r1) & 7;
  const long rt0 = (long)r0 * K + c0 * 8;
  const long rt1 = (long)r1 * K + c1 * 8;
  const unsigned short* Ab = A + m0 * K;
  const unsigned short* Bb = B + n0 * K;

  // frag-read constants (phys chunk = logical(quad + kc*4) ^ (row&7))
  const int rA = wm * 16 + l16;
  const int rB = wn * 16 + l16;
  const int chk0 = (quad ^ (l16 & 7)) * 8;
  const int chk1 = chk0 ^ 32;

  f32x4 acc[8][4];
#pragma unroll
  for (int a_ = 0; a_ < 8; ++a_)
#pragma unroll
    for (int b_ = 0; b_ < 4; ++b_) acc[a_][b_] = (f32x4){0.f, 0.f, 0.f, 0.f};

  auto stgA = [&](int b, int h, long kk) {
    const unsigned short* s = Ab + (long)h * 128 * K + kk;
    unsigned short* d = As + (b * 2 + h) * 8192 + wv * 512;
    async16(s + rt0, d);
    async16(s + rt1, d + 4096);
  };
  auto stgB = [&](int b, int h, long kk) {
    const unsigned short* s = Bb + (long)h * 128 * K + kk;
    unsigned short* d = Bs + (b * 2 + h) * 8192 + wv * 512;
    async16(s + rt0, d);
    async16(s + rt1, d + 4096);
  };

  // prologue: tile0 (8 loads, buf0) then u=tile1's B0,A0,B1 (6 loads, buf1)
  stgA(0, 0, 0); stgA(0, 1, 0); stgB(0, 0, 0); stgB(0, 1, 0);
  stgB(1, 0, 64); stgA(1, 0, 64); stgB(1, 1, 64);
  asm volatile("s_waitcnt vmcnt(6)" ::: "memory");   // tile0 landed
  __builtin_amdgcn_s_barrier();
  __builtin_amdgcn_sched_barrier(0);

  const int NI = K >> 7;   // K/128 (2 K-tiles per iter)
  for (int it = 0; it < NI; ++it) {
    const long kt  = (long)it * 128;
    const long ku  = kt + 64;
    const long kt2 = kt + 128;
    const long kt3 = kt + 192;
    const bool more = (it + 1 < NI);

    bf16x8 bq[2][2];
    // ---- p1: q0 of t (A0 x B0) ----
    {
      bf16x8 a[4][2];
      LDA4(a, 0, 0); LDB2(bq, 0, 0);
      stgA(1, 1, ku);                        // u.A1 (always needed)
      PH_MID();
      MFMA8(0, 0, a, bq);
      PH_END();
    }
    // ---- p2: q1 of t (A1 x B0, B held) ----
    {
      bf16x8 a[4][2];
      LDA4(a, 0, 1);
      if (more) stgB(0, 0, kt2);             // t2.B0 (B0 dead after p1)
      PH_MID();
      MFMA8(4, 0, a, bq);
      PH_END();
    }
    // ---- p3: q2 of t (A0 x B1) ----
    {
      bf16x8 a[4][2];
      LDA4(a, 0, 0); LDB2(bq, 0, 1);
      PH_MID();
      MFMA8(0, 2, a, bq);
      PH_END();
    }
    // ---- p4: q3 of t (A1 x B1, B held) ----
    {
      bf16x8 a[4][2];
      LDA4(a, 0, 1);
      if (more) { stgA(0, 0, kt2); stgB(0, 1, kt2); }  // t2.A0, t2.B1
      PH_MID();
      MFMA8(4, 2, a, bq);
      __builtin_amdgcn_s_setprio(0);
      __builtin_amdgcn_sched_barrier(0);
      if (more) { asm volatile("s_waitcnt vmcnt(6)" ::: "memory"); }  // u landed
      else      { asm volatile("s_waitcnt vmcnt(0)" ::: "memory"); }
      __builtin_amdgcn_s_barrier();
      __builtin_amdgcn_sched_barrier(0);
    }
    // ---- p5: q0 of u ----
    {
      bf16x8 a[4][2];
      LDA4(a, 1, 0); LDB2(bq, 1, 0);
      if (more) stgA(0, 1, kt2);             // t2.A1 (A1 dead after p4)
      PH_MID();
      MFMA8(0, 0, a, bq);
      PH_END();
    }
    // ---- p6: q1 of u ----
    {
      bf16x8 a[4][2];
      LDA4(a, 1, 1);
      if (more) stgB(1, 0, kt3);             // t3.B0
      PH_MID();
      MFMA8(4, 0, a, bq);
      PH_END();
    }
    // ---- p7: q2 of u ----
    {
      bf16x8 a[4][2];
      LDA4(a, 1, 0); LDB2(bq, 1, 1);
      PH_MID();
      MFMA8(0, 2, a, bq);
      PH_END();
    }
    // ---- p8: q3 of u ----
    {
      bf16x8 a[4][2];
      LDA4(a, 1, 1);
      if (more) { stgA(1, 0, kt3); stgB(1, 1, kt3); }  // t3.A0, t3.B1
      PH_MID();
      MFMA8(4, 2, a, bq);
      __builtin_amdgcn_s_setprio(0);
      __builtin_amdgcn_sched_barrier(0);
      if (more) { asm volatile("s_waitcnt vmcnt(6)" ::: "memory"); }  // t2 landed
      __builtin_amdgcn_s_barrier();
      __builtin_amdgcn_sched_barrier(0);
    }
  }

  // epilogue
#pragma unroll
  for (int nt = 0; nt < 4; ++nt) {
    const long col = n0 + nt * 64 + wn * 16 + l16;
    const float bv = (EPI == 2) ? bias[col] : 0.f;
    const float scl = (EPI == 3 && col < 1024) ? CQK : 1.0f;
#pragma unroll
    for (int mt = 0; mt < 8; ++mt) {
#pragma unroll
      for (int r = 0; r < 4; ++r) {
        const long row = m0 + mt * 32 + wm * 16 + quad * 4 + r;
        const long idx = row * (long)N + col;
        float v = acc[mt][nt][r];
        if (EPI == 2) {
          v += bv;
          ((unsigned short*)Cout)[idx] = f2bf(v > 0.f ? v : 0.f);
        } else {
          ((unsigned short*)Cout)[idx] = f2bf(v * scl);
        }
      }
    }
  }
}

// ---------------------------------------------------------------------------
// vprep: V (cols 2048.. of qkv) -> per-(b,h,kv-tile) async16-ready tiles.
// ---------------------------------------------------------------------------
__global__ void vprep(const unsigned short* __restrict__ qkv,
                      unsigned short* __restrict__ vt) {
  __shared__ unsigned short T[64 * 68];
  const int tid = threadIdx.x;           // 256
  const int t = blockIdx.x;              // kv tile 0..31
  const int bh = blockIdx.y;             // 0..63
  const int b = bh >> 4, h = bh & 15;
  const long base = ((long)b * 2048 + t * 64) * 3072 + 2048 + h * 64;
#pragma unroll
  for (int i = 0; i < 4; ++i) {
    int c = i * 256 + tid;
    int r = c >> 4, d4 = (c & 15) * 4;
    *(ushort4*)(T + r * 68 + d4) = *(const ushort4*)(qkv + base + (long)r * 3072 + d4);
  }
  __syncthreads();
  unsigned short* out = vt + ((long)bh * 32 + t) * 4096;
#pragma unroll
  for (int i = 0; i < 4; ++i) {
    int u = i * 256 + tid;               // ushort4 index 0..1023
    int c = u >> 1, half = u & 1;
    int d = c >> 3;
    int k = ((c & 7) - d) & 7;
    int kvp4 = k * 8 + half * 4;
    int sk = (kvp4 & 32) | ((kvp4 & 4) << 2) | ((kvp4 & 16) >> 1) | ((kvp4 & 8) >> 1);
    ushort4 o;
    o.x = T[(sk + 0) * 68 + d];
    o.y = T[(sk + 1) * 68 + d];
    o.z = T[(sk + 2) * 68 + d];
    o.w = T[(sk + 3) * 68 + d];
    *(ushort4*)(out + u * 4) = o;
  }
}

// ---------------------------------------------------------------------------
// Flash attention fwd, S^T formulation, fixed-base softmax. (unchanged)
// ---------------------------------------------------------------------------
__launch_bounds__(256, 3)
__global__ void attn_fwd(const unsigned short* __restrict__ qkv,
                         const unsigned short* __restrict__ vt,
                         unsigned short* __restrict__ outp) {
  __shared__ __align__(16) unsigned short Qs[128 * 64];  // 16 KB
  __shared__ __align__(16) unsigned short Ks[128 * 64];  // 16 KB
  __shared__ __align__(16) unsigned short Vs[128 * 64];  // 16 KB (2x 64-kv tiles)

  const int tid = threadIdx.x;
  const int lane = tid & 63;
  const int wv = __builtin_amdgcn_readfirstlane(tid >> 6);  // 0..3
  const int quad = lane >> 4, l16 = lane & 15;

  const int id = blockIdx.y * 16 + blockIdx.x;   // grid (16, 64)
  const int xcd = id & 7, slot = id >> 3;        // slot 0..127
  const int bh = xcd * 8 + (slot >> 4);
  const int qt = slot & 15;
  const int b = bh >> 4, h = bh & 15;
  const long rowbase = (long)b * 2048;
  const int hoff = h * 64;

  // ---- stage Q (128x64) via swizzled async16, 4 sets ----
  {
    const unsigned short* qsrc = qkv + (rowbase + qt * 128) * 3072 + hoff;
#pragma unroll
    for (int j = 0; j < 4; ++j) {
      const int c = j * 256 + wv * 64 + lane;
      const int row = c >> 3;
      const int k = ((c & 7) - row) & 7;
      async16(qsrc + (long)row * 3072 + k * 8, Qs + (j * 256 + wv * 64) * 8);
    }
  }
  __syncthreads();

  const int rot0 = (quad + l16) & 7;
  const int rot1 = rot0 ^ 4;

  // Q B-frags: strip s covers q = wv*32 + s*16 + l16 (loop-invariant)
  bf16x8 bq[2][2];
#pragma unroll
  for (int s = 0; s < 2; ++s) {
    const int qrow = wv * 32 + s * 16 + l16;
    bq[s][0] = *(const bf16x8*)(Qs + qrow * 64 + rot0 * 8);
    bq[s][1] = *(const bf16x8*)(Qs + qrow * 64 + rot1 * 8);
  }

  // staging constants (256 thr cover 1024 chunks in 4 sets)
  const int c0 = wv * 64 + lane;
  const int r0 = c0 >> 3;
  const int ks = ((c0 & 7) - r0) & 7;
  const unsigned short* kptr = qkv + (rowbase + r0) * 3072 + 1024 + hoff + ks * 8;
  const unsigned short* vptr = vt + (long)bh * 131072 + (long)c0 * 8;
  unsigned short* kdst = Ks + wv * 512;
  unsigned short* vdst = Vs + wv * 512;

  bf16x8 ones;
#pragma unroll
  for (int i = 0; i < 8; ++i) ones[i] = (short)0x3F80;

  f32x4 oacc[2][4], lacc[2];
#pragma unroll
  for (int s = 0; s < 2; ++s) {
    lacc[s] = (f32x4){0.f, 0.f, 0.f, 0.f};
#pragma unroll
    for (int i = 0; i < 4; ++i) oacc[s][i] = (f32x4){0.f, 0.f, 0.f, 0.f};
  }

  for (int kt = 0; kt < 16; ++kt) {
    __syncthreads();                      // prior iter's Ks/Vs reads complete
#pragma unroll
    for (int j = 0; j < 4; ++j) {
      async16(kptr + (long)j * 32 * 3072, kdst + j * 2048);
      async16(vptr + j * 2048, vdst + j * 2048);
    }
    kptr += (long)128 * 3072;
    vptr += 8192;
    __syncthreads();                      // drain async before frag reads

    // St = K.Q^T for both strips; ak frags shared
    f32x4 sacc[2][8];
#pragma unroll
    for (int t = 0; t < 8; ++t) {
      const int ar = t * 16 + l16;
      bf16x8 ak0 = *(const bf16x8*)(Ks + ar * 64 + rot0 * 8);
      bf16x8 ak1 = *(const bf16x8*)(Ks + ar * 64 + rot1 * 8);
#pragma unroll
      for (int s = 0; s < 2; ++s) {
        f32x4 z = (f32x4){0.f, 0.f, 0.f, 0.f};
        z = __builtin_amdgcn_mfma_f32_16x16x32_bf16(ak0, bq[s][0], z, 0, 0, 0);
        sacc[s][t] = __builtin_amdgcn_mfma_f32_16x16x32_bf16(ak1, bq[s][1], z, 0, 0, 0);
      }
    }

    // fixed-base softmax: p = exp2(s); pack to A-frags; l via ones-MFMA
    union APU { unsigned u[4]; bf16x8 v; } ap[2][4];
#pragma unroll
    for (int s = 0; s < 2; ++s)
#pragma unroll
      for (int hf = 0; hf < 4; ++hf) {
#pragma unroll
        for (int t = 0; t < 2; ++t) {
          const f32x4 sv = sacc[s][hf * 2 + t];
          const float p0 = __builtin_amdgcn_exp2f(sv[0]);
          const float p1 = __builtin_amdgcn_exp2f(sv[1]);
          const float p2 = __builtin_amdgcn_exp2f(sv[2]);
          const float p3 = __builtin_amdgcn_exp2f(sv[3]);
          ap[s][hf].u[t * 2 + 0] = pk2(p0, p1);
          ap[s][hf].u[t * 2 + 1] = pk2(p2, p3);
        }
        lacc[s] = __builtin_amdgcn_mfma_f32_16x16x32_bf16(ap[s][hf].v, ones,
                                                          lacc[s], 0, 0, 0);
      }

    // O += P.V : bv frags shared across both strips
#pragma unroll
    for (int hf = 0; hf < 4; ++hf) {
      const int vbase = (hf >> 1) * 4096 + ((hf & 1) ? rot1 : rot0) * 8;
#pragma unroll
      for (int dt = 0; dt < 4; ++dt) {
        bf16x8 bv = *(const bf16x8*)(Vs + vbase + (dt * 16 + l16) * 64);
#pragma unroll
        for (int s = 0; s < 2; ++s)
          oacc[s][dt] = __builtin_amdgcn_mfma_f32_16x16x32_bf16(ap[s][hf].v, bv,
                                                                oacc[s][dt], 0, 0, 0);
      }
    }
  }

  // epilogue: q-row = wv*32 + s*16 + quad*4 + r; lacc already in that layout
#pragma unroll
  for (int s = 0; s < 2; ++s) {
    float linv[4];
#pragma unroll
    for (int r = 0; r < 4; ++r) linv[r] = 1.f / lacc[s][r];
#pragma unroll
    for (int dt = 0; dt < 4; ++dt)
#pragma unroll
      for (int r = 0; r < 4; ++r) {
        const long row = rowbase + qt * 128 + wv * 32 + s * 16 + quad * 4 + r;
        outp[row * 1024 + hoff + dt * 16 + l16] = f2bf(oacc[s][dt][r] * linv[r]);
      }
  }
}

// ---------------------------------------------------------------------------
// launch
// ---------------------------------------------------------------------------
extern "C" void kernel_launch(void* const* d_in, const int* in_sizes, int n_in,
                              void* d_out, int out_size, void* d_ws, size_t ws_size,
                              hipStream_t stream) {
  (void)in_sizes; (void)n_in; (void)out_size; (void)ws_size;
  const float* x   = (const float*)d_in[0];
  const float* Wq  = (const float*)d_in[1];
  const float* Wk  = (const float*)d_in[2];
  const float* Wv  = (const float*)d_in[3];
  const float* Wo  = (const float*)d_in[4];
  const float* bo  = (const float*)d_in[5];
  const float* g1  = (const float*)d_in[6];
  const float* be1 = (const float*)d_in[7];
  const float* g2  = (const float*)d_in[8];
  const float* be2 = (const float*)d_in[9];
  const float* W1  = (const float*)d_in[10];
  const float* bf1 = (const float*)d_in[11];
  const float* W2  = (const float*)d_in[12];
  const float* bf2 = (const float*)d_in[13];

  static bool s_attr = false;
  if (!s_attr) {
    hipFuncSetAttribute(reinterpret_cast<const void*>(&gemm256<3>),
                        hipFuncAttributeMaxDynamicSharedMemorySize, 131072);
    hipFuncSetAttribute(reinterpret_cast<const void*>(&gemm256<2>),
                        hipFuncAttributeMaxDynamicSharedMemorySize, 131072);
    s_attr = true;
  }

  char* ws = (char*)d_ws;
  unsigned short* wqkv  = (unsigned short*)(ws);              // [3072,1024] bf16   6 MiB
  unsigned short* wo    = (unsigned short*)(ws + 6291456);    // [1024,1024]        2 MiB
  unsigned short* w1    = (unsigned short*)(ws + 8388608);    // [4096,1024]        8 MiB
  unsigned short* w2    = (unsigned short*)(ws + 16777216);   // [1024,4096]        8 MiB
  unsigned short* xn    = (unsigned short*)(ws + 25165824);   // [8192,1024]       16 MiB
  unsigned short* big   = (unsigned short*)(ws + 41943040);   // qkv/h             64 MiB
  unsigned short* attnb = (unsigned short*)(ws + 109051904);  // [8192,1024]       16 MiB
  float*          x1    = (float*)(ws + 125829120);           // [8192,1024] f32   32 MiB
  // vtg aliases xn: LN1's xn dead after QKV GEMM; attn consumes before LN2.
  unsigned short* vtg   = xn;                                 // [64][32][4096]    16 MiB

  cvt_all<<<12288, 256, 0, stream>>>(Wq, Wk, Wv, Wo, W1, W2, wqkv);

  ln_fwd<<<8192, 256, 0, stream>>>(x, g1, be1, xn);
  gemm256<3><<<dim3(384), 512, 131072, stream>>>(xn, wqkv, big, nullptr,
                                                 8192, 3072, 1024);
  vprep<<<dim3(32, 64), 256, 0, stream>>>(big, vtg);
  attn_fwd<<<dim3(16, 64), 256, 0, stream>>>(big, vtg, attnb);
  gemm_bt<1><<<dim3(8, 64), 256, 0, stream>>>(attnb, wo, x1, bo, x,
                                              8192, 1024, 1024);
  ln_fwd<<<8192, 256, 0, stream>>>(x1, g2, be2, xn);
  gemm256<2><<<dim3(512), 512, 131072, stream>>>(xn, w1, big, bf1,
                                                 8192, 4096, 1024);
  gemm_bt<1><<<dim3(8, 64), 256, 0, stream>>>(big, w2, (float*)d_out, bf2, x1,
                                              8192, 1024, 4096);
}

// Round 2
// 472.420 us; speedup vs baseline: 1.0329x; 1.0329x over previous
//
#include <hip/hip_runtime.h>
#include <hip/hip_bf16.h>
#include <cstdint>

// ---------------------------------------------------------------------------
// TransBlock: pre-LN transformer encoder block, bf16 MFMA compute, fp32 I/O.
// B=4 S=2048 E=1024 H=16 Dh=64 Dff=4096.  M = B*S = 8192 rows.
// ---------------------------------------------------------------------------

typedef __attribute__((ext_vector_type(8))) short bf16x8;   // 4 VGPRs, MFMA A/B frag
typedef __attribute__((ext_vector_type(4))) float f32x4;    // MFMA C/D frag

#define LDSAS __attribute__((address_space(3)))
#define GLBAS __attribute__((address_space(1)))

#define CQK 0.18033688011112044f   // (1/8) * log2(e), folded into Q at QKV epilogue

__device__ __forceinline__ unsigned short f2bf(float f) {
  union { float f; unsigned u; } c; c.f = f;
  unsigned u = c.u + 0x7fffu + ((c.u >> 16) & 1u);   // RNE
  return (unsigned short)(u >> 16);
}

__device__ __forceinline__ unsigned pk2(float a, float b) {  // v_cvt_pk path
  __hip_bfloat162 h = __float22bfloat162_rn(make_float2(a, b));
  union { __hip_bfloat162 h; unsigned u; } c; c.h = h; return c.u;
}

// async global->LDS, 16B/lane, dest = wave-uniform base + lane*16
__device__ __forceinline__ void async16(const unsigned short* g, unsigned short* l) {
  __builtin_amdgcn_global_load_lds((const GLBAS unsigned int*)g,
                                   (LDSAS unsigned int*)l, 16, 0, 0);
}

// ---------------------------------------------------------------------------
// cvt_all: all six fp32 weight arrays -> bf16 workspace in ONE launch.
// ---------------------------------------------------------------------------
__global__ void cvt_all(const float* __restrict__ q, const float* __restrict__ k,
                        const float* __restrict__ v, const float* __restrict__ o,
                        const float* __restrict__ w1, const float* __restrict__ w2,
                        unsigned short* __restrict__ wsb) {
  const long i = (long)blockIdx.x * 256 + threadIdx.x;   // float4 index
  const float* src; unsigned short* dst; long off;
  if (i < 1048576) {
    const long seg = i >> 18, o4 = i & 262143;
    src = (seg == 0) ? q : (seg == 1) ? k : (seg == 2) ? v : o;
    dst = wsb + ((seg == 3) ? 3145728L : seg * 1048576L);
    off = o4;
  } else if (i < 2097152) {
    src = w1; dst = wsb + 4194304; off = i - 1048576;
  } else {
    src = w2; dst = wsb + 8388608; off = i - 2097152;
  }
  const float4 vv = ((const float4*)src)[off];
  ushort4 r;
  r.x = f2bf(vv.x); r.y = f2bf(vv.y); r.z = f2bf(vv.z); r.w = f2bf(vv.w);
  ((ushort4*)dst)[off] = r;
}

// ---------------------------------------------------------------------------
// LayerNorm: one block per row of 1024, fp32 in -> bf16 out
// ---------------------------------------------------------------------------
__global__ void ln_fwd(const float* __restrict__ x, const float* __restrict__ g,
                       const float* __restrict__ bb, unsigned short* __restrict__ outp) {
  const int row = blockIdx.x, tid = threadIdx.x;
  const float4 v = ((const float4*)(x + (long)row * 1024))[tid];
  float s  = v.x + v.y + v.z + v.w;
  float sq = v.x * v.x + v.y * v.y + v.z * v.z + v.w * v.w;
#pragma unroll
  for (int off = 1; off < 64; off <<= 1) {
    s  += __shfl_xor(s, off);
    sq += __shfl_xor(sq, off);
  }
  __shared__ float red[8];
  const int wv = tid >> 6, lane = tid & 63;
  if (lane == 0) { red[wv] = s; red[4 + wv] = sq; }
  __syncthreads();
  s  = red[0] + red[1] + red[2] + red[3];
  sq = red[4] + red[5] + red[6] + red[7];
  const float mu  = s * (1.f / 1024.f);
  const float var = sq * (1.f / 1024.f) - mu * mu;
  const float rstd = rsqrtf(var + 1e-5f);
  const float4 gv = ((const float4*)g)[tid];
  const float4 bv = ((const float4*)bb)[tid];
  ushort4 o;
  o.x = f2bf((v.x - mu) * rstd * gv.x + bv.x);
  o.y = f2bf((v.y - mu) * rstd * gv.y + bv.y);
  o.z = f2bf((v.z - mu) * rstd * gv.z + bv.z);
  o.w = f2bf((v.w - mu) * rstd * gv.w + bv.w);
  ((ushort4*)(outp + (long)row * 1024))[tid] = o;
}

// ---------------------------------------------------------------------------
// B^T GEMM (128x128 tile, 2-barrier structure) kept for N=1024 GEMMs where a
// 256^2 grid would only fill half the CUs (Wo, W2).
// EPI: 1 = +bias +fp32 residual -> fp32
// ---------------------------------------------------------------------------
template <int EPI>
__launch_bounds__(256, 3)
__global__ void gemm_bt(const unsigned short* __restrict__ A,
                        const unsigned short* __restrict__ B,
                        void* __restrict__ Cout,
                        const float* __restrict__ bias,
                        const float* __restrict__ res,
                        int M, int N, int K) {
  __shared__ __align__(16) unsigned short As[128 * 64];   // 16 KB each
  __shared__ __align__(16) unsigned short Bs[128 * 64];
  const int tid  = threadIdx.x;
  const int lane = tid & 63;
  const int wvu  = __builtin_amdgcn_readfirstlane(tid >> 6);  // wave id, SGPR
  const int quad = lane >> 4, l16 = lane & 15;
  const int wm = wvu >> 1, wn = wvu & 1;

  const int gx = gridDim.x;
  const int id = blockIdx.y * gx + blockIdx.x;
  const int xcd = id & 7, slot = id >> 3;
  const int by = xcd * 8 + (slot & 7);
  const int bx = slot >> 3;
  const long m0 = (long)by * 128, n0 = (long)bx * 128;

  f32x4 acc[4][4];
#pragma unroll
  for (int i = 0; i < 4; i++)
#pragma unroll
    for (int j = 0; j < 4; j++) acc[i][j] = (f32x4){0.f, 0.f, 0.f, 0.f};

  const int rxA = l16 & 7;
  const int c0A = quad ^ rxA;              // kc=0 phys chunk for frag reads
  int srow[4], sgc[4];
#pragma unroll
  for (int j = 0; j < 4; ++j) {
    const int s = wvu * 256 + j * 64 + lane;
    srow[j] = s >> 3;
    sgc[j] = ((s & 7) ^ (srow[j] & 7)) * 8;
  }

  for (int k0 = 0; k0 < K; k0 += 64) {
    __syncthreads();
#pragma unroll
    for (int j = 0; j < 4; ++j) {
      const int db = (wvu * 256 + j * 64) * 8;   // wave-uniform LDS base (elems)
      async16(A + (m0 + srow[j]) * K + k0 + sgc[j], As + db);
      async16(B + (n0 + srow[j]) * K + k0 + sgc[j], Bs + db);
    }
    __syncthreads();

#pragma unroll
    for (int kc = 0; kc < 2; ++kc) {
      const int ch = (c0A ^ (kc * 4)) * 8;
      bf16x8 af[4], bfr[4];
#pragma unroll
      for (int t = 0; t < 4; ++t) {
        af[t]  = *(const bf16x8*)(As + (wm * 64 + t * 16 + l16) * 64 + ch);
        bfr[t] = *(const bf16x8*)(Bs + (wn * 64 + t * 16 + l16) * 64 + ch);
      }
#pragma unroll
      for (int mt = 0; mt < 4; ++mt)
#pragma unroll
        for (int nt = 0; nt < 4; ++nt)
          acc[mt][nt] = __builtin_amdgcn_mfma_f32_16x16x32_bf16(af[mt], bfr[nt],
                                                                acc[mt][nt], 0, 0, 0);
    }
  }

#pragma unroll
  for (int nt = 0; nt < 4; ++nt) {
    const long col = n0 + wn * 64 + nt * 16 + l16;
    float bv = 0.f;
    if (EPI == 1 || EPI == 2) bv = bias[col];
    const float scl = (EPI == 3 && col < 1024) ? CQK : 1.0f;
#pragma unroll
    for (int mt = 0; mt < 4; ++mt) {
#pragma unroll
      for (int r = 0; r < 4; ++r) {
        const long row = m0 + wm * 64 + mt * 16 + quad * 4 + r;
        const long idx = row * (long)N + col;
        float v = acc[mt][nt][r];
        if (EPI == 0) {
          ((unsigned short*)Cout)[idx] = f2bf(v);
        } else if (EPI == 1) {
          ((float*)Cout)[idx] = v + bv + res[idx];
        } else if (EPI == 2) {
          v += bv;
          ((unsigned short*)Cout)[idx] = f2bf(v > 0.f ? v : 0.f);
        } else {
          ((unsigned short*)Cout)[idx] = f2bf(v * scl);
        }
      }
    }
  }
}

// ---------------------------------------------------------------------------
// gemm256 v2: 256x256 tile, BK=64, 8-phase counted-vmcnt schedule.
// CHANGE vs v1: quadrant order q00->q01->q11->q10 with A-halves and B1 HELD in
// registers across adjacent phases; only B0 is re-read (p4).  LDS ds_read_b128
// per wave per K-tile: 40 -> 28 (12/4/8/4 per phase).  At m134's measured
// ds_read_b128 throughput (~85 B/cy/CU) v1 was LDS-read-BW-bound (3770 cyc LDS
// vs 2480 cyc MFMA per K-tile); v2 is MFMA-bound (~2700 <= 2480 borderline).
//
// Staging re-derived for the new half-death order (X staged into the LDS slot
// that died the previous phase):
//   p1: u.B0 (always)   p2: t2.A0   p3: t2.B1   p4: t2.A1 ; vmcnt(6)
//   p5: t2.B0           p6: t3.A0   p7: t3.B1   p8: t3.A1 ; vmcnt(6)
// Induction: after each p4/p8 vmcnt(6), outstanding = {next tile's A0,B1,A1}.
// EPI: 2 = +bias, relu -> bf16 ; 3 = bf16, cols<1024 scaled by CQK
// ---------------------------------------------------------------------------
#define LDA4(AF, BUF, H)                                                        \
  do {                                                                          \
    const unsigned short* _p = As + ((BUF) * 2 + (H)) * 8192;                   \
    _Pragma("unroll") for (int _m = 0; _m < 4; ++_m) {                          \
      AF[_m][0] = *(const bf16x8*)(_p + (_m * 32 + rA) * 64 + chk0);            \
      AF[_m][1] = *(const bf16x8*)(_p + (_m * 32 + rA) * 64 + chk1);            \
    }                                                                           \
  } while (0)

#define LDB2(BF, BUF, H)                                                        \
  do {                                                                          \
    const unsigned short* _p = Bs + ((BUF) * 2 + (H)) * 8192;                   \
    _Pragma("unroll") for (int _n = 0; _n < 2; ++_n) {                          \
      BF[_n][0] = *(const bf16x8*)(_p + (_n * 64 + rB) * 64 + chk0);            \
      BF[_n][1] = *(const bf16x8*)(_p + (_n * 64 + rB) * 64 + chk1);            \
    }                                                                           \
  } while (0)

#define MFMA8(MB, NB, AF, BF)                                                   \
  do {                                                                          \
    _Pragma("unroll") for (int _m = 0; _m < 4; ++_m)                            \
    _Pragma("unroll") for (int _n = 0; _n < 2; ++_n) {                          \
      acc[(MB) + _m][(NB) + _n] = __builtin_amdgcn_mfma_f32_16x16x32_bf16(      \
          AF[_m][0], BF[_n][0], acc[(MB) + _m][(NB) + _n], 0, 0, 0);            \
      acc[(MB) + _m][(NB) + _n] = __builtin_amdgcn_mfma_f32_16x16x32_bf16(      \
          AF[_m][1], BF[_n][1], acc[(MB) + _m][(NB) + _n], 0, 0, 0);            \
    }                                                                           \
  } while (0)

#define PH_MID()                                                                \
  __builtin_amdgcn_s_barrier();                                                 \
  asm volatile("s_waitcnt lgkmcnt(0)" ::: "memory");                            \
  __builtin_amdgcn_sched_barrier(0);                                            \
  __builtin_amdgcn_s_setprio(1)

#define PH_END()                                                                \
  __builtin_amdgcn_s_setprio(0);                                                \
  __builtin_amdgcn_sched_barrier(0);                                            \
  __builtin_amdgcn_s_barrier();                                                 \
  __builtin_amdgcn_sched_barrier(0)

template <int EPI>
__launch_bounds__(512, 2)
__global__ void gemm256(const unsigned short* __restrict__ A,
                        const unsigned short* __restrict__ B,
                        void* __restrict__ Cout,
                        const float* __restrict__ bias,
                        int M, int N, int K) {
  extern __shared__ __align__(16) unsigned short lds[];
  unsigned short* As = lds;            // [2 buf][2 half][8192]  64 KB
  unsigned short* Bs = lds + 32768;    // [2 buf][2 half][8192]  64 KB

  const int tid  = threadIdx.x;
  const int lane = tid & 63;
  const int wv   = __builtin_amdgcn_readfirstlane(tid >> 6);  // 0..7
  const int quad = lane >> 4, l16 = lane & 15;
  const int wm = wv >> 2, wn = wv & 3;

  // XCD-aware remap: 32 m-tiles, each XCD owns a 4-tile m-band
  const int id = blockIdx.x;
  const int xcd = id & 7, slot = id >> 3;
  const int by = xcd * 4 + (slot & 3);
  const int bx = slot >> 2;
  const long m0 = (long)by * 256, n0 = (long)bx * 256;

  // staging constants: chunk s = j*512 + wv*64 + lane; row=s>>3, phys=s&7,
  // source logical chunk = phys ^ (row&7)
  const int s0 = wv * 64 + lane;
  const int r0 = s0 >> 3;
  const int c0 = (s0 ^ r0) & 7;
  const int s1 = 512 + s0;
  const int r1 = s1 >> 3;
  const int c1 = (s1 ^ r1) & 7;
  const long rt0 = (long)r0 * K + c0 * 8;
  const long rt1 = (long)r1 * K + c1 * 8;
  const unsigned short* Ab = A + m0 * K;
  const unsigned short* Bb = B + n0 * K;

  // frag-read constants (phys chunk = logical(quad + kc*4) ^ (row&7))
  const int rA = wm * 16 + l16;
  const int rB = wn * 16 + l16;
  const int chk0 = (quad ^ (l16 & 7)) * 8;
  const int chk1 = chk0 ^ 32;

  f32x4 acc[8][4];
#pragma unroll
  for (int a_ = 0; a_ < 8; ++a_)
#pragma unroll
    for (int b_ = 0; b_ < 4; ++b_) acc[a_][b_] = (f32x4){0.f, 0.f, 0.f, 0.f};

  auto stgA = [&](int b, int h, long kk) {
    const unsigned short* s = Ab + (long)h * 128 * K + kk;
    unsigned short* d = As + (b * 2 + h) * 8192 + wv * 512;
    async16(s + rt0, d);
    async16(s + rt1, d + 4096);
  };
  auto stgB = [&](int b, int h, long kk) {
    const unsigned short* s = Bb + (long)h * 128 * K + kk;
    unsigned short* d = Bs + (b * 2 + h) * 8192 + wv * 512;
    async16(s + rt0, d);
    async16(s + rt1, d + 4096);
  };

  // prologue: tile0 fully (8 loads, buf0), then tile1's A0,B1,A1 (6, buf1).
  // tile1.B0 is staged in iter0's p1.
  stgA(0, 0, 0); stgB(0, 1, 0); stgA(0, 1, 0); stgB(0, 0, 0);
  stgA(1, 0, 64); stgB(1, 1, 64); stgA(1, 1, 64);
  asm volatile("s_waitcnt vmcnt(6)" ::: "memory");   // tile0 landed
  __builtin_amdgcn_s_barrier();
  __builtin_amdgcn_sched_barrier(0);

  const int NI = K >> 7;   // K/128 (2 K-tiles per iter)
  for (int it = 0; it < NI; ++it) {
    const long kt  = (long)it * 128;
    const long ku  = kt + 64;
    const long kt2 = kt + 128;
    const long kt3 = kt + 192;
    const bool more = (it + 1 < NI);

    // ================= tile t (buf0) =================
    {
      bf16x8 a0[4][2], a1[4][2], b0[2][2], b1[2][2];
      // p1: q00 = A0 x B0   (12 ds_read)
      LDA4(a0, 0, 0); LDB2(b0, 0, 0);
      stgB(1, 0, ku);                        // u.B0 (always; u.B0 LDS died at prev p8)
      PH_MID();
      MFMA8(0, 0, a0, b0);
      PH_END();
      // p2: q01 = A0 x B1   (4 ds_read; a0 held)
      LDB2(b1, 0, 1);
      if (more) stgA(0, 0, kt2);             // t2.A0 (t.A0 died after p1)
      PH_MID();
      MFMA8(0, 2, a0, b1);
      PH_END();
      // p3: q11 = A1 x B1   (8 ds_read; b1 held)
      LDA4(a1, 0, 1);
      if (more) stgB(0, 1, kt2);             // t2.B1 (t.B1 died after p2)
      PH_MID();
      MFMA8(4, 2, a1, b1);
      PH_END();
      // p4: q10 = A1 x B0   (4 ds_read re-read B0; a1 held)
      LDB2(b0, 0, 0);
      if (more) stgA(0, 1, kt2);             // t2.A1 (t.A1 died after p3)
      PH_MID();
      MFMA8(4, 0, a1, b0);
      __builtin_amdgcn_s_setprio(0);
      __builtin_amdgcn_sched_barrier(0);
      if (more) { asm volatile("s_waitcnt vmcnt(6)" ::: "memory"); }  // u landed
      else      { asm volatile("s_waitcnt vmcnt(0)" ::: "memory"); }
      __builtin_amdgcn_s_barrier();
      __builtin_amdgcn_sched_barrier(0);
    }
    // ================= tile u (buf1) =================
    {
      bf16x8 a0[4][2], a1[4][2], b0[2][2], b1[2][2];
      // p5: q00
      LDA4(a0, 1, 0); LDB2(b0, 1, 0);
      if (more) stgB(0, 0, kt2);             // t2.B0 (t.B0 died after p4)
      PH_MID();
      MFMA8(0, 0, a0, b0);
      PH_END();
      // p6: q01
      LDB2(b1, 1, 1);
      if (more) stgA(1, 0, kt3);             // t3.A0 (u.A0 died after p5)
      PH_MID();
      MFMA8(0, 2, a0, b1);
      PH_END();
      // p7: q11
      LDA4(a1, 1, 1);
      if (more) stgB(1, 1, kt3);             // t3.B1 (u.B1 died after p6)
      PH_MID();
      MFMA8(4, 2, a1, b1);
      PH_END();
      // p8: q10
      LDB2(b0, 1, 0);
      if (more) stgA(1, 1, kt3);             // t3.A1 (u.A1 died after p7)
      PH_MID();
      MFMA8(4, 0, a1, b0);
      __builtin_amdgcn_s_setprio(0);
      __builtin_amdgcn_sched_barrier(0);
      if (more) { asm volatile("s_waitcnt vmcnt(6)" ::: "memory"); }  // t2 landed
      __builtin_amdgcn_s_barrier();
      __builtin_amdgcn_sched_barrier(0);
    }
  }

  // epilogue
#pragma unroll
  for (int nt = 0; nt < 4; ++nt) {
    const long col = n0 + nt * 64 + wn * 16 + l16;
    const float bv = (EPI == 2) ? bias[col] : 0.f;
    const float scl = (EPI == 3 && col < 1024) ? CQK : 1.0f;
#pragma unroll
    for (int mt = 0; mt < 8; ++mt) {
#pragma unroll
      for (int r = 0; r < 4; ++r) {
        const long row = m0 + mt * 32 + wm * 16 + quad * 4 + r;
        const long idx = row * (long)N + col;
        float v = acc[mt][nt][r];
        if (EPI == 2) {
          v += bv;
          ((unsigned short*)Cout)[idx] = f2bf(v > 0.f ? v : 0.f);
        } else {
          ((unsigned short*)Cout)[idx] = f2bf(v * scl);
        }
      }
    }
  }
}

// ---------------------------------------------------------------------------
// vprep: V (cols 2048.. of qkv) -> per-(b,h,kv-tile) async16-ready tiles.
// ---------------------------------------------------------------------------
__global__ void vprep(const unsigned short* __restrict__ qkv,
                      unsigned short* __restrict__ vt) {
  __shared__ unsigned short T[64 * 68];
  const int tid = threadIdx.x;           // 256
  const int t = blockIdx.x;              // kv tile 0..31
  const int bh = blockIdx.y;             // 0..63
  const int b = bh >> 4, h = bh & 15;
  const long base = ((long)b * 2048 + t * 64) * 3072 + 2048 + h * 64;
#pragma unroll
  for (int i = 0; i < 4; ++i) {
    int c = i * 256 + tid;
    int r = c >> 4, d4 = (c & 15) * 4;
    *(ushort4*)(T + r * 68 + d4) = *(const ushort4*)(qkv + base + (long)r * 3072 + d4);
  }
  __syncthreads();
  unsigned short* out = vt + ((long)bh * 32 + t) * 4096;
#pragma unroll
  for (int i = 0; i < 4; ++i) {
    int u = i * 256 + tid;               // ushort4 index 0..1023
    int c = u >> 1, half = u & 1;
    int d = c >> 3;
    int k = ((c & 7) - d) & 7;
    int kvp4 = k * 8 + half * 4;
    int sk = (kvp4 & 32) | ((kvp4 & 4) << 2) | ((kvp4 & 16) >> 1) | ((kvp4 & 8) >> 1);
    ushort4 o;
    o.x = T[(sk + 0) * 68 + d];
    o.y = T[(sk + 1) * 68 + d];
    o.z = T[(sk + 2) * 68 + d];
    o.w = T[(sk + 3) * 68 + d];
    *(ushort4*)(out + u * 4) = o;
  }
}

// ---------------------------------------------------------------------------
// Flash attention fwd, S^T formulation, fixed-base softmax. (unchanged)
// ---------------------------------------------------------------------------
__launch_bounds__(256, 3)
__global__ void attn_fwd(const unsigned short* __restrict__ qkv,
                         const unsigned short* __restrict__ vt,
                         unsigned short* __restrict__ outp) {
  __shared__ __align__(16) unsigned short Qs[128 * 64];  // 16 KB
  __shared__ __align__(16) unsigned short Ks[128 * 64];  // 16 KB
  __shared__ __align__(16) unsigned short Vs[128 * 64];  // 16 KB (2x 64-kv tiles)

  const int tid = threadIdx.x;
  const int lane = tid & 63;
  const int wv = __builtin_amdgcn_readfirstlane(tid >> 6);  // 0..3
  const int quad = lane >> 4, l16 = lane & 15;

  const int id = blockIdx.y * 16 + blockIdx.x;   // grid (16, 64)
  const int xcd = id & 7, slot = id >> 3;        // slot 0..127
  const int bh = xcd * 8 + (slot >> 4);
  const int qt = slot & 15;
  const int b = bh >> 4, h = bh & 15;
  const long rowbase = (long)b * 2048;
  const int hoff = h * 64;

  // ---- stage Q (128x64) via swizzled async16, 4 sets ----
  {
    const unsigned short* qsrc = qkv + (rowbase + qt * 128) * 3072 + hoff;
#pragma unroll
    for (int j = 0; j < 4; ++j) {
      const int c = j * 256 + wv * 64 + lane;
      const int row = c >> 3;
      const int k = ((c & 7) - row) & 7;
      async16(qsrc + (long)row * 3072 + k * 8, Qs + (j * 256 + wv * 64) * 8);
    }
  }
  __syncthreads();

  const int rot0 = (quad + l16) & 7;
  const int rot1 = rot0 ^ 4;

  // Q B-frags: strip s covers q = wv*32 + s*16 + l16 (loop-invariant)
  bf16x8 bq[2][2];
#pragma unroll
  for (int s = 0; s < 2; ++s) {
    const int qrow = wv * 32 + s * 16 + l16;
    bq[s][0] = *(const bf16x8*)(Qs + qrow * 64 + rot0 * 8);
    bq[s][1] = *(const bf16x8*)(Qs + qrow * 64 + rot1 * 8);
  }

  // staging constants (256 thr cover 1024 chunks in 4 sets)
  const int c0 = wv * 64 + lane;
  const int r0 = c0 >> 3;
  const int ks = ((c0 & 7) - r0) & 7;
  const unsigned short* kptr = qkv + (rowbase + r0) * 3072 + 1024 + hoff + ks * 8;
  const unsigned short* vptr = vt + (long)bh * 131072 + (long)c0 * 8;
  unsigned short* kdst = Ks + wv * 512;
  unsigned short* vdst = Vs + wv * 512;

  bf16x8 ones;
#pragma unroll
  for (int i = 0; i < 8; ++i) ones[i] = (short)0x3F80;

  f32x4 oacc[2][4], lacc[2];
#pragma unroll
  for (int s = 0; s < 2; ++s) {
    lacc[s] = (f32x4){0.f, 0.f, 0.f, 0.f};
#pragma unroll
    for (int i = 0; i < 4; ++i) oacc[s][i] = (f32x4){0.f, 0.f, 0.f, 0.f};
  }

  for (int kt = 0; kt < 16; ++kt) {
    __syncthreads();                      // prior iter's Ks/Vs reads complete
#pragma unroll
    for (int j = 0; j < 4; ++j) {
      async16(kptr + (long)j * 32 * 3072, kdst + j * 2048);
      async16(vptr + j * 2048, vdst + j * 2048);
    }
    kptr += (long)128 * 3072;
    vptr += 8192;
    __syncthreads();                      // drain async before frag reads

    // St = K.Q^T for both strips; ak frags shared
    f32x4 sacc[2][8];
#pragma unroll
    for (int t = 0; t < 8; ++t) {
      const int ar = t * 16 + l16;
      bf16x8 ak0 = *(const bf16x8*)(Ks + ar * 64 + rot0 * 8);
      bf16x8 ak1 = *(const bf16x8*)(Ks + ar * 64 + rot1 * 8);
#pragma unroll
      for (int s = 0; s < 2; ++s) {
        f32x4 z = (f32x4){0.f, 0.f, 0.f, 0.f};
        z = __builtin_amdgcn_mfma_f32_16x16x32_bf16(ak0, bq[s][0], z, 0, 0, 0);
        sacc[s][t] = __builtin_amdgcn_mfma_f32_16x16x32_bf16(ak1, bq[s][1], z, 0, 0, 0);
      }
    }

    // fixed-base softmax: p = exp2(s); pack to A-frags; l via ones-MFMA
    union APU { unsigned u[4]; bf16x8 v; } ap[2][4];
#pragma unroll
    for (int s = 0; s < 2; ++s)
#pragma unroll
      for (int hf = 0; hf < 4; ++hf) {
#pragma unroll
        for (int t = 0; t < 2; ++t) {
          const f32x4 sv = sacc[s][hf * 2 + t];
          const float p0 = __builtin_amdgcn_exp2f(sv[0]);
          const float p1 = __builtin_amdgcn_exp2f(sv[1]);
          const float p2 = __builtin_amdgcn_exp2f(sv[2]);
          const float p3 = __builtin_amdgcn_exp2f(sv[3]);
          ap[s][hf].u[t * 2 + 0] = pk2(p0, p1);
          ap[s][hf].u[t * 2 + 1] = pk2(p2, p3);
        }
        lacc[s] = __builtin_amdgcn_mfma_f32_16x16x32_bf16(ap[s][hf].v, ones,
                                                          lacc[s], 0, 0, 0);
      }

    // O += P.V : bv frags shared across both strips
#pragma unroll
    for (int hf = 0; hf < 4; ++hf) {
      const int vbase = (hf >> 1) * 4096 + ((hf & 1) ? rot1 : rot0) * 8;
#pragma unroll
      for (int dt = 0; dt < 4; ++dt) {
        bf16x8 bv = *(const bf16x8*)(Vs + vbase + (dt * 16 + l16) * 64);
#pragma unroll
        for (int s = 0; s < 2; ++s)
          oacc[s][dt] = __builtin_amdgcn_mfma_f32_16x16x32_bf16(ap[s][hf].v, bv,
                                                                oacc[s][dt], 0, 0, 0);
      }
    }
  }

  // epilogue: q-row = wv*32 + s*16 + quad*4 + r; lacc already in that layout
#pragma unroll
  for (int s = 0; s < 2; ++s) {
    float linv[4];
#pragma unroll
    for (int r = 0; r < 4; ++r) linv[r] = 1.f / lacc[s][r];
#pragma unroll
    for (int dt = 0; dt < 4; ++dt)
#pragma unroll
      for (int r = 0; r < 4; ++r) {
        const long row = rowbase + qt * 128 + wv * 32 + s * 16 + quad * 4 + r;
        outp[row * 1024 + hoff + dt * 16 + l16] = f2bf(oacc[s][dt][r] * linv[r]);
      }
  }
}

// ---------------------------------------------------------------------------
// launch
// ---------------------------------------------------------------------------
extern "C" void kernel_launch(void* const* d_in, const int* in_sizes, int n_in,
                              void* d_out, int out_size, void* d_ws, size_t ws_size,
                              hipStream_t stream) {
  (void)in_sizes; (void)n_in; (void)out_size; (void)ws_size;
  const float* x   = (const float*)d_in[0];
  const float* Wq  = (const float*)d_in[1];
  const float* Wk  = (const float*)d_in[2];
  const float* Wv  = (const float*)d_in[3];
  const float* Wo  = (const float*)d_in[4];
  const float* bo  = (const float*)d_in[5];
  const float* g1  = (const float*)d_in[6];
  const float* be1 = (const float*)d_in[7];
  const float* g2  = (const float*)d_in[8];
  const float* be2 = (const float*)d_in[9];
  const float* W1  = (const float*)d_in[10];
  const float* bf1 = (const float*)d_in[11];
  const float* W2  = (const float*)d_in[12];
  const float* bf2 = (const float*)d_in[13];

  static bool s_attr = false;
  if (!s_attr) {
    hipFuncSetAttribute(reinterpret_cast<const void*>(&gemm256<3>),
                        hipFuncAttributeMaxDynamicSharedMemorySize, 131072);
    hipFuncSetAttribute(reinterpret_cast<const void*>(&gemm256<2>),
                        hipFuncAttributeMaxDynamicSharedMemorySize, 131072);
    s_attr = true;
  }

  char* ws = (char*)d_ws;
  unsigned short* wqkv  = (unsigned short*)(ws);              // [3072,1024] bf16   6 MiB
  unsigned short* wo    = (unsigned short*)(ws + 6291456);    // [1024,1024]        2 MiB
  unsigned short* w1    = (unsigned short*)(ws + 8388608);    // [4096,1024]        8 MiB
  unsigned short* w2    = (unsigned short*)(ws + 16777216);   // [1024,4096]        8 MiB
  unsigned short* xn    = (unsigned short*)(ws + 25165824);   // [8192,1024]       16 MiB
  unsigned short* big   = (unsigned short*)(ws + 41943040);   // qkv/h             64 MiB
  unsigned short* attnb = (unsigned short*)(ws + 109051904);  // [8192,1024]       16 MiB
  float*          x1    = (float*)(ws + 125829120);           // [8192,1024] f32   32 MiB
  // vtg aliases xn: LN1's xn dead after QKV GEMM; attn consumes before LN2.
  unsigned short* vtg   = xn;                                 // [64][32][4096]    16 MiB

  cvt_all<<<12288, 256, 0, stream>>>(Wq, Wk, Wv, Wo, W1, W2, wqkv);

  ln_fwd<<<8192, 256, 0, stream>>>(x, g1, be1, xn);
  gemm256<3><<<dim3(384), 512, 131072, stream>>>(xn, wqkv, big, nullptr,
                                                 8192, 3072, 1024);
  vprep<<<dim3(32, 64), 256, 0, stream>>>(big, vtg);
  attn_fwd<<<dim3(16, 64), 256, 0, stream>>>(big, vtg, attnb);
  gemm_bt<1><<<dim3(8, 64), 256, 0, stream>>>(attnb, wo, x1, bo, x,
                                              8192, 1024, 1024);
  ln_fwd<<<8192, 256, 0, stream>>>(x1, g2, be2, xn);
  gemm256<2><<<dim3(512), 512, 131072, stream>>>(xn, w1, big, bf1,
                                                 8192, 4096, 1024);
  gemm_bt<1><<<dim3(8, 64), 256, 0, stream>>>(big, w2, (float*)d_out, bf2, x1,
                                              8192, 1024, 4096);
}